// Round 2
// baseline (218.657 us; speedup 1.0000x reference)
//
#include <hip/hip_runtime.h>

#define GS 128
#define GS3 2097152          // 128^3
#define NS1 262144           // 64^3
#define NS2 32768            // 32^3
#define NS3 4096             // 16^3
#define NS4 512              // 8^3
#define NS5 64               // 4^3

// Output element offsets (float index) for each scale's block of [Ss^3, 12]
#define OB0 0
#define OB1 25165824
#define OB2 28311552
#define OB3 28704768
#define OB4 28753920
#define OB5 28760064

// ---------------------------------------------------------------------------
// 1) Scatter: one packed u32 atomicAdd per point.  bits[31:20]=count, [19:0]=sum of (label+1)
//    Sums are exact small integers -> order-independent, bit-deterministic.
// ---------------------------------------------------------------------------
__global__ __launch_bounds__(256) void scatter_kernel(
    const int* __restrict__ coords, const float* __restrict__ inst,
    unsigned int* __restrict__ P, int N) {
  int i = blockIdx.x * blockDim.x + threadIdx.x;
  if (i >= N) return;
  int x = coords[3 * i + 0];
  int y = coords[3 * i + 1];
  int z = coords[3 * i + 2];
  unsigned lab = (unsigned)inst[i] + 1u;           // labels are exact integers 0..49
  atomicAdd(&P[(x << 14) + (y << 7) + z], (1u << 20) | lab);
}

// ---------------------------------------------------------------------------
// 2) Pool 128^3 -> 64^3 in double: vsum = sum val (val = s/c exact rational / f64),
//    asum = count of active fine voxels.
// ---------------------------------------------------------------------------
__global__ __launch_bounds__(256) void pool1_kernel(
    const unsigned int* __restrict__ P,
    double* __restrict__ vs1, double* __restrict__ as1) {
  int q = blockIdx.x * blockDim.x + threadIdx.x;
  if (q >= NS1) return;
  int X = q >> 12, Y = (q >> 6) & 63, Z = q & 63;
  double vs = 0.0, as = 0.0;
#pragma unroll
  for (int dx = 0; dx < 2; dx++)
#pragma unroll
    for (int dy = 0; dy < 2; dy++)
#pragma unroll
      for (int dz = 0; dz < 2; dz++) {
        int p = (((2 * X + dx) << 14) + ((2 * Y + dy) << 7) + (2 * Z + dz));
        unsigned pk = P[p];
        unsigned c = pk >> 20;
        if (c) {
          vs += (double)(pk & 0xFFFFFu) / (double)c;
          as += 1.0;
        }
      }
  vs1[q] = vs;
  as1[q] = as;
}

// ---------------------------------------------------------------------------
// 3) Pool scales 2..5 directly from scale-1 sums (sums are additive).
//    L2: 1 thread/output (8 children).  L3: 1 thread/output (64 children).
//    L4: 1 wave/output (512 children).  L5: 1 wave/output (4096 children).
// ---------------------------------------------------------------------------
__global__ __launch_bounds__(256) void poolRest_kernel(
    const double* __restrict__ vs1, const double* __restrict__ as1,
    double* __restrict__ vs2, double* __restrict__ as2,
    double* __restrict__ vs3, double* __restrict__ as3,
    double* __restrict__ vs4, double* __restrict__ as4,
    double* __restrict__ vs5, double* __restrict__ as5) {
  int t = blockIdx.x * blockDim.x + threadIdx.x;

  if (t < NS2) {  // scale 2: 32^3 outputs, 2^3 children on the 64-grid
    int q = t;
    int X = q >> 10, Y = (q >> 5) & 31, Z = q & 31;
    double vs = 0.0, as = 0.0;
#pragma unroll
    for (int dx = 0; dx < 2; dx++)
#pragma unroll
      for (int dy = 0; dy < 2; dy++)
#pragma unroll
        for (int dz = 0; dz < 2; dz++) {
          int p = ((((X << 1) + dx) << 12) + (((Y << 1) + dy) << 6) + ((Z << 1) + dz));
          vs += vs1[p];
          as += as1[p];
        }
    vs2[q] = vs;
    as2[q] = as;
    return;
  }
  t -= NS2;
  if (t < NS3) {  // scale 3: 16^3 outputs, 4^3 children
    int q = t;
    int X = q >> 8, Y = (q >> 4) & 15, Z = q & 15;
    double vs = 0.0, as = 0.0;
    for (int dx = 0; dx < 4; dx++)
      for (int dy = 0; dy < 4; dy++)
#pragma unroll
        for (int dz = 0; dz < 4; dz++) {
          int p = ((((X << 2) + dx) << 12) + (((Y << 2) + dy) << 6) + ((Z << 2) + dz));
          vs += vs1[p];
          as += as1[p];
        }
    vs3[q] = vs;
    as3[q] = as;
    return;
  }
  t -= NS3;
  if (t < NS4 * 64) {  // scale 4: 8^3 outputs, 8^3=512 children, one wave each
    int w = t >> 6, lane = t & 63;
    int X = w >> 6, Y = (w >> 3) & 7, Z = w & 7;
    double vs = 0.0, as = 0.0;
#pragma unroll
    for (int j = 0; j < 8; j++) {
      int c = lane * 8 + j;                    // child linear index in 8^3
      int dx = c >> 6, dy = (c >> 3) & 7, dz = c & 7;
      int p = ((((X << 3) + dx) << 12) + (((Y << 3) + dy) << 6) + ((Z << 3) + dz));
      vs += vs1[p];
      as += as1[p];
    }
    for (int o = 32; o > 0; o >>= 1) {
      vs += __shfl_down(vs, o, 64);
      as += __shfl_down(as, o, 64);
    }
    if (lane == 0) { vs4[w] = vs; as4[w] = as; }
    return;
  }
  t -= NS4 * 64;
  if (t < NS5 * 64) {  // scale 5: 4^3 outputs, 16^3=4096 children, one wave each
    int w = t >> 6, lane = t & 63;
    int X = w >> 4, Y = (w >> 2) & 3, Z = w & 3;
    double vs = 0.0, as = 0.0;
    for (int j = 0; j < 64; j++) {
      int c = lane * 64 + j;                   // child linear index in 16^3
      int dx = c >> 8, dy = (c >> 4) & 15, dz = c & 15;
      int p = ((((X << 4) + dx) << 12) + (((Y << 4) + dy) << 6) + ((Z << 4) + dz));
      vs += vs1[p];
      as += as1[p];
    }
    for (int o = 32; o > 0; o >>= 1) {
      vs += __shfl_down(vs, o, 64);
      as += __shfl_down(as, o, 64);
    }
    if (lane == 0) { vs5[w] = vs; as5[w] = as; }
  }
}

// ---------------------------------------------------------------------------
// 4) Scale-0 output: exact integer comparison
//    |sn/cn - sc/cc| < 0.01  <=>  100*|sn*cc - sc*cn| < cn*cc   (all ints, no FP)
// ---------------------------------------------------------------------------
__global__ __launch_bounds__(256) void out0_kernel(
    const unsigned int* __restrict__ P, float* __restrict__ out) {
  int p = blockIdx.x * blockDim.x + threadIdx.x;
  if (p >= GS3) return;
  unsigned pk = P[p];
  int cc = (int)(pk >> 20);
  float4 r0 = {0.f, 0.f, 0.f, 0.f}, r1 = r0, r2 = r0;
  if (cc) {
    int sc = (int)(pk & 0xFFFFFu);
    int x = p >> 14, y = (p >> 7) & 127, z = p & 127;
    const int off[6] = {-(1 << 14), (1 << 14), -(1 << 7), (1 << 7), -1, 1};
    const bool inb[6] = {x > 0, x < 127, y > 0, y < 127, z > 0, z < 127};
    float f[6], m[6];
#pragma unroll
    for (int k = 0; k < 6; k++) {
      int sn = 0, cn = 0;
      if (inb[k]) {
        unsigned pn = P[p + off[k]];
        cn = (int)(pn >> 20);
        sn = (int)(pn & 0xFFFFFu);
      }
      if (cn) {
        int d = sn * cc - sc * cn;             // |d| <= 750*4095 < 2^31
        if (d < 0) d = -d;
        f[k] = (100 * d < cn * cc) ? 1.f : 0.f;
        m[k] = 1.f;
      } else {
        f[k] = 0.f;                            // vc >= 1 so |0-vc| >= 1
        m[k] = 0.f;
      }
    }
    r0 = {f[0], f[1], f[2], f[3]};
    r1 = {f[4], f[5], m[0], m[1]};
    r2 = {m[2], m[3], m[4], m[5]};
  }
  float4* o = (float4*)(out + 12ll * p);
  o[0] = r0; o[1] = r1; o[2] = r2;
}

// ---------------------------------------------------------------------------
// 5) Coarse-scale outputs (scales 1..5), f64 divisions + comparisons.
// ---------------------------------------------------------------------------
__global__ __launch_bounds__(256) void outCoarse_kernel(
    const double* __restrict__ vs1, const double* __restrict__ as1,
    const double* __restrict__ vs2, const double* __restrict__ as2,
    const double* __restrict__ vs3, const double* __restrict__ as3,
    const double* __restrict__ vs4, const double* __restrict__ as4,
    const double* __restrict__ vs5, const double* __restrict__ as5,
    float* __restrict__ out) {
  int t = blockIdx.x * blockDim.x + threadIdx.x;
  const double *vs, *as;
  int ls, q;
  long long obase;
  if (t < NS1) { q = t; vs = vs1; as = as1; ls = 6; obase = OB1; }
  else if (t < NS1 + NS2) { q = t - NS1; vs = vs2; as = as2; ls = 5; obase = OB2; }
  else if (t < NS1 + NS2 + NS3) { q = t - NS1 - NS2; vs = vs3; as = as3; ls = 4; obase = OB3; }
  else if (t < NS1 + NS2 + NS3 + NS4) { q = t - NS1 - NS2 - NS3; vs = vs4; as = as4; ls = 3; obase = OB4; }
  else if (t < NS1 + NS2 + NS3 + NS4 + NS5) { q = t - NS1 - NS2 - NS3 - NS4; vs = vs5; as = as5; ls = 2; obase = OB5; }
  else return;

  int Ss = 1 << ls;
  int X = q >> (2 * ls), Y = (q >> ls) & (Ss - 1), Z = q & (Ss - 1);
  double ac = as[q];
  float4 r0 = {0.f, 0.f, 0.f, 0.f}, r1 = r0, r2 = r0;
  if (ac > 0.0) {
    double vc = vs[q] / ac;
    const int off[6] = {-(Ss * Ss), Ss * Ss, -Ss, Ss, -1, 1};
    const bool inb[6] = {X > 0, X < Ss - 1, Y > 0, Y < Ss - 1, Z > 0, Z < Ss - 1};
    float f[6], m[6];
#pragma unroll
    for (int k = 0; k < 6; k++) {
      double van = 0.0;
      if (inb[k]) {
        double an = as[q + off[k]];
        if (an > 0.0) van = vs[q + off[k]] / an;   // va = v (>=1) if active else 0
      }
      f[k] = (fabs(van - vc) < 0.01) ? 1.f : 0.f;
      m[k] = (van > 0.0) ? 1.f : 0.f;
    }
    r0 = {f[0], f[1], f[2], f[3]};
    r1 = {f[4], f[5], m[0], m[1]};
    r2 = {m[2], m[3], m[4], m[5]};
  }
  float4* o = (float4*)(out + obase + 12ll * q);
  o[0] = r0; o[1] = r1; o[2] = r2;
}

// ---------------------------------------------------------------------------
extern "C" void kernel_launch(void* const* d_in, const int* in_sizes, int n_in,
                              void* d_out, int out_size, void* d_ws, size_t ws_size,
                              hipStream_t stream) {
  const int* coords = (const int*)d_in[0];
  const float* inst = (const float*)d_in[1];
  int N = in_sizes[1];            // 4,000,000 points
  float* out = (float*)d_out;

  // workspace layout
  unsigned int* P = (unsigned int*)d_ws;                 // u32[128^3] = 8 MB
  char* base = (char*)d_ws;
  double* vs1 = (double*)(base + 8388608);
  double* as1 = vs1 + NS1;
  double* vs2 = as1 + NS1; double* as2 = vs2 + NS2;
  double* vs3 = as2 + NS2; double* as3 = vs3 + NS3;
  double* vs4 = as3 + NS3; double* as4 = vs4 + NS4;
  double* vs5 = as4 + NS4; double* as5 = vs5 + NS5;     // ends at ~12.6 MB

  hipMemsetAsync(P, 0, (size_t)GS3 * 4, stream);
  scatter_kernel<<<(N + 255) / 256, 256, 0, stream>>>(coords, inst, P, N);
  pool1_kernel<<<NS1 / 256, 256, 0, stream>>>(P, vs1, as1);
  poolRest_kernel<<<(NS2 + NS3 + NS4 * 64 + NS5 * 64) / 256, 256, 0, stream>>>(
      vs1, as1, vs2, as2, vs3, as3, vs4, as4, vs5, as5);
  out0_kernel<<<GS3 / 256, 256, 0, stream>>>(P, out);
  outCoarse_kernel<<<(NS1 + NS2 + NS3 + NS4 + NS5 + 255) / 256, 256, 0, stream>>>(
      vs1, as1, vs2, as2, vs3, as3, vs4, as4, vs5, as5, out);
}

// Round 3
// 118.542 us; speedup vs baseline: 1.8446x; 1.8446x over previous
//
#include <hip/hip_runtime.h>

#define GS3 2097152          // 128^3
#define NS1 262144           // 64^3
#define NS2 32768            // 32^3
#define NS3 4096             // 16^3
#define NS4 512              // 8^3
#define NS5 64               // 4^3

// Output element offsets (float index) for each scale's block of [Ss^3, 12]
#define OB1 25165824
#define OB2 28311552
#define OB3 28704768
#define OB4 28753920
#define OB5 28760064

#define NREG 512             // regions: x (7b) * y-quadrant (2b)
#define RVOX 4096            // voxels per region: 32 (y) * 128 (z)
#define CAP  10240           // bin capacity per region (mean 7813, +27 sigma)
#define PPB  8192            // points per binning block

// ---------------------------------------------------------------------------
// 1a) Binning: group points by region with per-block LDS histograms.
//     Record: (region<<18) | (localvoxel<<6) | label,  localvoxel=(y&31)<<7|z
// ---------------------------------------------------------------------------
__global__ __launch_bounds__(256) void bin_kernel(
    const int* __restrict__ coords, const float* __restrict__ inst,
    unsigned int* __restrict__ cnt, unsigned int* __restrict__ bins, int N) {
  __shared__ unsigned int lrec[PPB];     // 32 KB staged records
  __shared__ unsigned int hist[NREG];    // 2 KB
  __shared__ unsigned int basec[NREG];   // 2 KB
  int tid = threadIdx.x;
  int start = blockIdx.x * PPB;
  for (int j = tid; j < NREG; j += 256) hist[j] = 0;
  __syncthreads();
  // phase 1: read points, build records in LDS, count per region
#pragma unroll
  for (int j = 0; j < PPB / 256; j++) {
    int i = start + j * 256 + tid;
    unsigned v = 0xFFFFFFFFu;
    if (i < N) {
      int x = coords[3 * i + 0];
      int y = coords[3 * i + 1];
      int z = coords[3 * i + 2];
      unsigned lab = (unsigned)inst[i] + 1u;                 // 1..50
      unsigned r = ((unsigned)x << 2) | ((unsigned)y >> 5);  // 9 bits
      v = (r << 18) | ((((unsigned)(y & 31) << 7) | (unsigned)z) << 6) | lab;
      atomicAdd(&hist[r], 1u);
    }
    lrec[j * 256 + tid] = v;
  }
  __syncthreads();
  // phase 2: reserve per-region chunks in global bins (few atomics, hot addrs)
  for (int j = tid; j < NREG; j += 256) {
    unsigned h = hist[j];
    basec[j] = h ? atomicAdd(&cnt[j], h) : 0u;
  }
  __syncthreads();
  for (int j = tid; j < NREG; j += 256) hist[j] = 0;   // reuse as cursor
  __syncthreads();
  // phase 3: write records grouped by region (frontier-local stores)
#pragma unroll
  for (int j = 0; j < PPB / 256; j++) {
    unsigned v = lrec[j * 256 + tid];
    if (v != 0xFFFFFFFFu) {
      unsigned r = v >> 18;
      unsigned p = basec[r] + atomicAdd(&hist[r], 1u);
      if (p < CAP) bins[r * CAP + p] = v & 0x3FFFFu;
    }
  }
}

// ---------------------------------------------------------------------------
// 1b) Build P: one block per region, aggregate records in a 16KB LDS grid
//     (packed cnt<<20|sum, integer adds -> order-independent), coalesced store.
// ---------------------------------------------------------------------------
__global__ __launch_bounds__(256) void build_kernel(
    const unsigned int* __restrict__ cnt, const unsigned int* __restrict__ bins,
    unsigned int* __restrict__ P) {
  __shared__ unsigned int grid[RVOX];    // 16 KB
  int r = blockIdx.x;
  int tid = threadIdx.x;
  for (int j = tid; j < RVOX; j += 256) grid[j] = 0;
  __syncthreads();
  int n = min((int)cnt[r], CAP);
  for (int k = tid; k < n; k += 256) {
    unsigned v = bins[r * CAP + k];
    atomicAdd(&grid[v >> 6], (1u << 20) | (v & 63u));
  }
  __syncthreads();
  unsigned baseoff = ((unsigned)(r >> 2) << 14) | ((unsigned)(r & 3) << 12);
  for (int j = tid; j < RVOX; j += 256) P[baseoff + j] = grid[j];
}

// ---------------------------------------------------------------------------
// 1-fallback) direct atomic scatter (used only if ws_size too small for bins)
// ---------------------------------------------------------------------------
__global__ __launch_bounds__(256) void scatter_kernel(
    const int* __restrict__ coords, const float* __restrict__ inst,
    unsigned int* __restrict__ P, int N) {
  int i = blockIdx.x * blockDim.x + threadIdx.x;
  if (i >= N) return;
  int x = coords[3 * i + 0];
  int y = coords[3 * i + 1];
  int z = coords[3 * i + 2];
  unsigned lab = (unsigned)inst[i] + 1u;
  atomicAdd(&P[(x << 14) + (y << 7) + z], (1u << 20) | lab);
}

// ---------------------------------------------------------------------------
// 2) Pool 128^3 -> 64^3 in double
// ---------------------------------------------------------------------------
__global__ __launch_bounds__(256) void pool1_kernel(
    const unsigned int* __restrict__ P,
    double* __restrict__ vs1, double* __restrict__ as1) {
  int q = blockIdx.x * blockDim.x + threadIdx.x;
  if (q >= NS1) return;
  int X = q >> 12, Y = (q >> 6) & 63, Z = q & 63;
  double vs = 0.0, as = 0.0;
#pragma unroll
  for (int dx = 0; dx < 2; dx++)
#pragma unroll
    for (int dy = 0; dy < 2; dy++)
#pragma unroll
      for (int dz = 0; dz < 2; dz++) {
        int p = (((2 * X + dx) << 14) + ((2 * Y + dy) << 7) + (2 * Z + dz));
        unsigned pk = P[p];
        unsigned c = pk >> 20;
        if (c) {
          vs += (double)(pk & 0xFFFFFu) / (double)c;
          as += 1.0;
        }
      }
  vs1[q] = vs;
  as1[q] = as;
}

// ---------------------------------------------------------------------------
// 3) Pool scales 2..5 from scale-1 sums (sums are additive).
// ---------------------------------------------------------------------------
__global__ __launch_bounds__(256) void poolRest_kernel(
    const double* __restrict__ vs1, const double* __restrict__ as1,
    double* __restrict__ vs2, double* __restrict__ as2,
    double* __restrict__ vs3, double* __restrict__ as3,
    double* __restrict__ vs4, double* __restrict__ as4,
    double* __restrict__ vs5, double* __restrict__ as5) {
  int t = blockIdx.x * blockDim.x + threadIdx.x;

  if (t < NS2) {
    int q = t;
    int X = q >> 10, Y = (q >> 5) & 31, Z = q & 31;
    double vs = 0.0, as = 0.0;
#pragma unroll
    for (int dx = 0; dx < 2; dx++)
#pragma unroll
      for (int dy = 0; dy < 2; dy++)
#pragma unroll
        for (int dz = 0; dz < 2; dz++) {
          int p = ((((X << 1) + dx) << 12) + (((Y << 1) + dy) << 6) + ((Z << 1) + dz));
          vs += vs1[p];
          as += as1[p];
        }
    vs2[q] = vs;
    as2[q] = as;
    return;
  }
  t -= NS2;
  if (t < NS3) {
    int q = t;
    int X = q >> 8, Y = (q >> 4) & 15, Z = q & 15;
    double vs = 0.0, as = 0.0;
    for (int dx = 0; dx < 4; dx++)
      for (int dy = 0; dy < 4; dy++)
#pragma unroll
        for (int dz = 0; dz < 4; dz++) {
          int p = ((((X << 2) + dx) << 12) + (((Y << 2) + dy) << 6) + ((Z << 2) + dz));
          vs += vs1[p];
          as += as1[p];
        }
    vs3[q] = vs;
    as3[q] = as;
    return;
  }
  t -= NS3;
  if (t < NS4 * 64) {
    int w = t >> 6, lane = t & 63;
    int X = w >> 6, Y = (w >> 3) & 7, Z = w & 7;
    double vs = 0.0, as = 0.0;
#pragma unroll
    for (int j = 0; j < 8; j++) {
      int c = lane * 8 + j;
      int dx = c >> 6, dy = (c >> 3) & 7, dz = c & 7;
      int p = ((((X << 3) + dx) << 12) + (((Y << 3) + dy) << 6) + ((Z << 3) + dz));
      vs += vs1[p];
      as += as1[p];
    }
    for (int o = 32; o > 0; o >>= 1) {
      vs += __shfl_down(vs, o, 64);
      as += __shfl_down(as, o, 64);
    }
    if (lane == 0) { vs4[w] = vs; as4[w] = as; }
    return;
  }
  t -= NS4 * 64;
  if (t < NS5 * 64) {
    int w = t >> 6, lane = t & 63;
    int X = w >> 4, Y = (w >> 2) & 3, Z = w & 3;
    double vs = 0.0, as = 0.0;
    for (int j = 0; j < 64; j++) {
      int c = lane * 64 + j;
      int dx = c >> 8, dy = (c >> 4) & 15, dz = c & 15;
      int p = ((((X << 4) + dx) << 12) + (((Y << 4) + dy) << 6) + ((Z << 4) + dz));
      vs += vs1[p];
      as += as1[p];
    }
    for (int o = 32; o > 0; o >>= 1) {
      vs += __shfl_down(vs, o, 64);
      as += __shfl_down(as, o, 64);
    }
    if (lane == 0) { vs5[w] = vs; as5[w] = as; }
  }
}

// ---------------------------------------------------------------------------
// 4) Scale-0 output: exact integer comparison (64-bit products for safety)
//    |sn/cn - sc/cc| < 0.01  <=>  100*|sn*cc - sc*cn| < cn*cc
// ---------------------------------------------------------------------------
__global__ __launch_bounds__(256) void out0_kernel(
    const unsigned int* __restrict__ P, float* __restrict__ out) {
  int p = blockIdx.x * blockDim.x + threadIdx.x;
  if (p >= GS3) return;
  unsigned pk = P[p];
  int cc = (int)(pk >> 20);
  float4 r0 = {0.f, 0.f, 0.f, 0.f}, r1 = r0, r2 = r0;
  if (cc) {
    int sc = (int)(pk & 0xFFFFFu);
    int x = p >> 14, y = (p >> 7) & 127, z = p & 127;
    const int off[6] = {-(1 << 14), (1 << 14), -(1 << 7), (1 << 7), -1, 1};
    const bool inb[6] = {x > 0, x < 127, y > 0, y < 127, z > 0, z < 127};
    float f[6], m[6];
#pragma unroll
    for (int k = 0; k < 6; k++) {
      int sn = 0, cn = 0;
      if (inb[k]) {
        unsigned pn = P[p + off[k]];
        cn = (int)(pn >> 20);
        sn = (int)(pn & 0xFFFFFu);
      }
      if (cn) {
        long long d = (long long)sn * cc - (long long)sc * cn;
        if (d < 0) d = -d;
        f[k] = (100ll * d < (long long)cn * cc) ? 1.f : 0.f;
        m[k] = 1.f;
      } else {
        f[k] = 0.f;                            // vc >= 1 so |0-vc| >= 1
        m[k] = 0.f;
      }
    }
    r0 = {f[0], f[1], f[2], f[3]};
    r1 = {f[4], f[5], m[0], m[1]};
    r2 = {m[2], m[3], m[4], m[5]};
  }
  float4* o = (float4*)(out + 12ll * p);
  o[0] = r0; o[1] = r1; o[2] = r2;
}

// ---------------------------------------------------------------------------
// 5) Coarse-scale outputs (scales 1..5), f64 divisions + comparisons.
// ---------------------------------------------------------------------------
__global__ __launch_bounds__(256) void outCoarse_kernel(
    const double* __restrict__ vs1, const double* __restrict__ as1,
    const double* __restrict__ vs2, const double* __restrict__ as2,
    const double* __restrict__ vs3, const double* __restrict__ as3,
    const double* __restrict__ vs4, const double* __restrict__ as4,
    const double* __restrict__ vs5, const double* __restrict__ as5,
    float* __restrict__ out) {
  int t = blockIdx.x * blockDim.x + threadIdx.x;
  const double *vs, *as;
  int ls, q;
  long long obase;
  if (t < NS1) { q = t; vs = vs1; as = as1; ls = 6; obase = OB1; }
  else if (t < NS1 + NS2) { q = t - NS1; vs = vs2; as = as2; ls = 5; obase = OB2; }
  else if (t < NS1 + NS2 + NS3) { q = t - NS1 - NS2; vs = vs3; as = as3; ls = 4; obase = OB3; }
  else if (t < NS1 + NS2 + NS3 + NS4) { q = t - NS1 - NS2 - NS3; vs = vs4; as = as4; ls = 3; obase = OB4; }
  else if (t < NS1 + NS2 + NS3 + NS4 + NS5) { q = t - NS1 - NS2 - NS3 - NS4; vs = vs5; as = as5; ls = 2; obase = OB5; }
  else return;

  int Ss = 1 << ls;
  int X = q >> (2 * ls), Y = (q >> ls) & (Ss - 1), Z = q & (Ss - 1);
  double ac = as[q];
  float4 r0 = {0.f, 0.f, 0.f, 0.f}, r1 = r0, r2 = r0;
  if (ac > 0.0) {
    double vc = vs[q] / ac;
    const int off[6] = {-(Ss * Ss), Ss * Ss, -Ss, Ss, -1, 1};
    const bool inb[6] = {X > 0, X < Ss - 1, Y > 0, Y < Ss - 1, Z > 0, Z < Ss - 1};
    float f[6], m[6];
#pragma unroll
    for (int k = 0; k < 6; k++) {
      double van = 0.0;
      if (inb[k]) {
        double an = as[q + off[k]];
        if (an > 0.0) van = vs[q + off[k]] / an;
      }
      f[k] = (fabs(van - vc) < 0.01) ? 1.f : 0.f;
      m[k] = (van > 0.0) ? 1.f : 0.f;
    }
    r0 = {f[0], f[1], f[2], f[3]};
    r1 = {f[4], f[5], m[0], m[1]};
    r2 = {m[2], m[3], m[4], m[5]};
  }
  float4* o = (float4*)(out + obase + 12ll * q);
  o[0] = r0; o[1] = r1; o[2] = r2;
}

// ---------------------------------------------------------------------------
extern "C" void kernel_launch(void* const* d_in, const int* in_sizes, int n_in,
                              void* d_out, int out_size, void* d_ws, size_t ws_size,
                              hipStream_t stream) {
  const int* coords = (const int*)d_in[0];
  const float* inst = (const float*)d_in[1];
  int N = in_sizes[1];            // 4,000,000 points
  float* out = (float*)d_out;

  // workspace layout
  char* base = (char*)d_ws;
  unsigned int* P = (unsigned int*)base;                 // 8 MB
  double* vs1 = (double*)(base + 8388608);
  double* as1 = vs1 + NS1;
  double* vs2 = as1 + NS1; double* as2 = vs2 + NS2;
  double* vs3 = as2 + NS2; double* as3 = vs3 + NS3;
  double* vs4 = as3 + NS3; double* as4 = vs4 + NS4;
  double* vs5 = as4 + NS4; double* as5 = vs5 + NS5;     // ends ~13.18 MB
  size_t cnt_off = 13182976;                             // 1KB-aligned
  unsigned int* cnt  = (unsigned int*)(base + cnt_off);
  unsigned int* bins = (unsigned int*)(base + cnt_off + 2048);
  size_t need = cnt_off + 2048 + (size_t)NREG * CAP * 4; // ~34.2 MB

  if (ws_size >= need) {
    hipMemsetAsync(cnt, 0, NREG * 4, stream);
    bin_kernel<<<(N + PPB - 1) / PPB, 256, 0, stream>>>(coords, inst, cnt, bins, N);
    build_kernel<<<NREG, 256, 0, stream>>>(cnt, bins, P);
  } else {
    hipMemsetAsync(P, 0, (size_t)GS3 * 4, stream);
    scatter_kernel<<<(N + 255) / 256, 256, 0, stream>>>(coords, inst, P, N);
  }
  pool1_kernel<<<NS1 / 256, 256, 0, stream>>>(P, vs1, as1);
  poolRest_kernel<<<(NS2 + NS3 + NS4 * 64 + NS5 * 64) / 256, 256, 0, stream>>>(
      vs1, as1, vs2, as2, vs3, as3, vs4, as4, vs5, as5);
  out0_kernel<<<GS3 / 256, 256, 0, stream>>>(P, out);
  outCoarse_kernel<<<(NS1 + NS2 + NS3 + NS4 + NS5 + 255) / 256, 256, 0, stream>>>(
      vs1, as1, vs2, as2, vs3, as3, vs4, as4, vs5, as5, out);
}

// Round 6
// 112.786 us; speedup vs baseline: 1.9387x; 1.0510x over previous
//
#include <hip/hip_runtime.h>

#define GS3 2097152          // 128^3
#define NS1 262144           // 64^3
#define NS2 32768            // 32^3
#define NS3 4096             // 16^3
#define NS4 512              // 8^3
#define NS5 64               // 4^3
#define NSALL 299584         // NS1+NS2+NS3+NS4+NS5

// Output element offsets (float index) for each scale's block of [Ss^3, 12]
#define OB1 25165824
#define OB2 28311552
#define OB3 28704768
#define OB4 28753920
#define OB5 28760064

#define NREG 512             // regions: x (7b) * y-quadrant (2b)
#define RVOX 4096            // voxels per region: 32 (y) * 128 (z)
#define CAP  10240           // bin capacity per region (mean 7813, +27 sigma)
#define PPB  8192            // points per binning block

// ---------------------------------------------------------------------------
// 0) Zero the 512-word region-counter array (custom kernel: the runtime's
//    2KB fillBufferAligned blit cost ~67us in-graph; this costs ~1.5us).
// ---------------------------------------------------------------------------
__global__ __launch_bounds__(256) void zero_cnt_kernel(unsigned int* __restrict__ cnt) {
  cnt[threadIdx.x] = 0u;
  cnt[threadIdx.x + 256] = 0u;
}

// ---------------------------------------------------------------------------
// 1a) Binning: group points by region with per-block LDS histograms.
//     Record: (region<<18) | (localvoxel<<6) | label,  localvoxel=(y&31)<<7|z
// ---------------------------------------------------------------------------
__global__ __launch_bounds__(256) void bin_kernel(
    const int* __restrict__ coords, const float* __restrict__ inst,
    unsigned int* __restrict__ cnt, unsigned int* __restrict__ bins, int N) {
  __shared__ unsigned int lrec[PPB];     // 32 KB staged records
  __shared__ unsigned int hist[NREG];    // 2 KB
  __shared__ unsigned int basec[NREG];   // 2 KB
  int tid = threadIdx.x;
  int start = blockIdx.x * PPB;
  for (int j = tid; j < NREG; j += 256) hist[j] = 0;
  __syncthreads();
  // phase 1: read points, build records in LDS, count per region
#pragma unroll
  for (int j = 0; j < PPB / 256; j++) {
    int i = start + j * 256 + tid;
    unsigned v = 0xFFFFFFFFu;
    if (i < N) {
      int x = coords[3 * i + 0];
      int y = coords[3 * i + 1];
      int z = coords[3 * i + 2];
      unsigned lab = (unsigned)inst[i] + 1u;                 // 1..50
      unsigned r = ((unsigned)x << 2) | ((unsigned)y >> 5);  // 9 bits
      v = (r << 18) | ((((unsigned)(y & 31) << 7) | (unsigned)z) << 6) | lab;
      atomicAdd(&hist[r], 1u);
    }
    lrec[j * 256 + tid] = v;
  }
  __syncthreads();
  // phase 2: reserve per-region chunks in global bins (few atomics, hot addrs)
  for (int j = tid; j < NREG; j += 256) {
    unsigned h = hist[j];
    basec[j] = h ? atomicAdd(&cnt[j], h) : 0u;
  }
  __syncthreads();
  for (int j = tid; j < NREG; j += 256) hist[j] = 0;   // reuse as cursor
  __syncthreads();
  // phase 3: write records grouped by region (frontier-local stores)
#pragma unroll
  for (int j = 0; j < PPB / 256; j++) {
    unsigned v = lrec[j * 256 + tid];
    if (v != 0xFFFFFFFFu) {
      unsigned r = v >> 18;
      unsigned p = basec[r] + atomicAdd(&hist[r], 1u);
      if (p < CAP) bins[r * CAP + p] = v & 0x3FFFFu;
    }
  }
}

// ---------------------------------------------------------------------------
// 1b) Build P: one block per region, aggregate records in a 16KB LDS grid
//     (packed cnt<<20|sum, integer adds -> order-independent), coalesced store.
// ---------------------------------------------------------------------------
__global__ __launch_bounds__(256) void build_kernel(
    const unsigned int* __restrict__ cnt, const unsigned int* __restrict__ bins,
    unsigned int* __restrict__ P) {
  __shared__ unsigned int grid[RVOX];    // 16 KB
  int r = blockIdx.x;
  int tid = threadIdx.x;
  for (int j = tid; j < RVOX; j += 256) grid[j] = 0;
  __syncthreads();
  int n = min((int)cnt[r], CAP);
  for (int k = tid; k < n; k += 256) {
    unsigned v = bins[r * CAP + k];
    atomicAdd(&grid[v >> 6], (1u << 20) | (v & 63u));
  }
  __syncthreads();
  unsigned baseoff = ((unsigned)(r >> 2) << 14) | ((unsigned)(r & 3) << 12);
  for (int j = tid; j < RVOX; j += 256) P[baseoff + j] = grid[j];
}

// ---------------------------------------------------------------------------
// 1-fallback) direct atomic scatter (used only if ws_size too small for bins)
// ---------------------------------------------------------------------------
__global__ __launch_bounds__(256) void scatter_kernel(
    const int* __restrict__ coords, const float* __restrict__ inst,
    unsigned int* __restrict__ P, int N) {
  int i = blockIdx.x * blockDim.x + threadIdx.x;
  if (i >= N) return;
  int x = coords[3 * i + 0];
  int y = coords[3 * i + 1];
  int z = coords[3 * i + 2];
  unsigned lab = (unsigned)inst[i] + 1u;
  atomicAdd(&P[(x << 14) + (y << 7) + z], (1u << 20) | lab);
}

// ---------------------------------------------------------------------------
// 2) Pool 128^3 -> 64^3 in double
// ---------------------------------------------------------------------------
__global__ __launch_bounds__(256) void pool1_kernel(
    const unsigned int* __restrict__ P,
    double* __restrict__ vs1, double* __restrict__ as1) {
  int q = blockIdx.x * blockDim.x + threadIdx.x;
  if (q >= NS1) return;
  int X = q >> 12, Y = (q >> 6) & 63, Z = q & 63;
  double vs = 0.0, as = 0.0;
#pragma unroll
  for (int dx = 0; dx < 2; dx++)
#pragma unroll
    for (int dy = 0; dy < 2; dy++)
#pragma unroll
      for (int dz = 0; dz < 2; dz++) {
        int p = (((2 * X + dx) << 14) + ((2 * Y + dy) << 7) + (2 * Z + dz));
        unsigned pk = P[p];
        unsigned c = pk >> 20;
        if (c) {
          vs += (double)(pk & 0xFFFFFu) / (double)c;
          as += 1.0;
        }
      }
  vs1[q] = vs;
  as1[q] = as;
}

// ---------------------------------------------------------------------------
// 3) Pool scales 2..5 from scale-1 sums (sums are additive).
// ---------------------------------------------------------------------------
__global__ __launch_bounds__(256) void poolRest_kernel(
    const double* __restrict__ vs1, const double* __restrict__ as1,
    double* __restrict__ vs2, double* __restrict__ as2,
    double* __restrict__ vs3, double* __restrict__ as3,
    double* __restrict__ vs4, double* __restrict__ as4,
    double* __restrict__ vs5, double* __restrict__ as5) {
  int t = blockIdx.x * blockDim.x + threadIdx.x;

  if (t < NS2) {
    int q = t;
    int X = q >> 10, Y = (q >> 5) & 31, Z = q & 31;
    double vs = 0.0, as = 0.0;
#pragma unroll
    for (int dx = 0; dx < 2; dx++)
#pragma unroll
      for (int dy = 0; dy < 2; dy++)
#pragma unroll
        for (int dz = 0; dz < 2; dz++) {
          int p = ((((X << 1) + dx) << 12) + (((Y << 1) + dy) << 6) + ((Z << 1) + dz));
          vs += vs1[p];
          as += as1[p];
        }
    vs2[q] = vs;
    as2[q] = as;
    return;
  }
  t -= NS2;
  if (t < NS3) {
    int q = t;
    int X = q >> 8, Y = (q >> 4) & 15, Z = q & 15;
    double vs = 0.0, as = 0.0;
    for (int dx = 0; dx < 4; dx++)
      for (int dy = 0; dy < 4; dy++)
#pragma unroll
        for (int dz = 0; dz < 4; dz++) {
          int p = ((((X << 2) + dx) << 12) + (((Y << 2) + dy) << 6) + ((Z << 2) + dz));
          vs += vs1[p];
          as += as1[p];
        }
    vs3[q] = vs;
    as3[q] = as;
    return;
  }
  t -= NS3;
  if (t < NS4 * 64) {
    int w = t >> 6, lane = t & 63;
    int X = w >> 6, Y = (w >> 3) & 7, Z = w & 7;
    double vs = 0.0, as = 0.0;
#pragma unroll
    for (int j = 0; j < 8; j++) {
      int c = lane * 8 + j;
      int dx = c >> 6, dy = (c >> 3) & 7, dz = c & 7;
      int p = ((((X << 3) + dx) << 12) + (((Y << 3) + dy) << 6) + ((Z << 3) + dz));
      vs += vs1[p];
      as += as1[p];
    }
    for (int o = 32; o > 0; o >>= 1) {
      vs += __shfl_down(vs, o, 64);
      as += __shfl_down(as, o, 64);
    }
    if (lane == 0) { vs4[w] = vs; as4[w] = as; }
    return;
  }
  t -= NS4 * 64;
  if (t < NS5 * 64) {
    int w = t >> 6, lane = t & 63;
    int X = w >> 4, Y = (w >> 2) & 3, Z = w & 3;
    double vs = 0.0, as = 0.0;
    for (int j = 0; j < 64; j++) {
      int c = lane * 64 + j;
      int dx = c >> 8, dy = (c >> 4) & 15, dz = c & 15;
      int p = ((((X << 4) + dx) << 12) + (((Y << 4) + dy) << 6) + ((Z << 4) + dz));
      vs += vs1[p];
      as += as1[p];
    }
    for (int o = 32; o > 0; o >>= 1) {
      vs += __shfl_down(vs, o, 64);
      as += __shfl_down(as, o, 64);
    }
    if (lane == 0) { vs5[w] = vs; as5[w] = as; }
  }
}

// ---------------------------------------------------------------------------
// 4) Fused output kernel.
//    Threads [0, GS3): scale-0 via exact integer comparison
//      |sn/cn - sc/cc| < 0.01  <=>  100*|sn*cc - sc*cn| < cn*cc
//    Threads [GS3, GS3+NSALL): scales 1..5 via f64.
// ---------------------------------------------------------------------------
__global__ __launch_bounds__(256) void out_kernel(
    const unsigned int* __restrict__ P,
    const double* __restrict__ vs1, const double* __restrict__ as1,
    const double* __restrict__ vs2, const double* __restrict__ as2,
    const double* __restrict__ vs3, const double* __restrict__ as3,
    const double* __restrict__ vs4, const double* __restrict__ as4,
    const double* __restrict__ vs5, const double* __restrict__ as5,
    float* __restrict__ out) {
  int p = blockIdx.x * blockDim.x + threadIdx.x;
  if (p < GS3) {
    unsigned pk = P[p];
    int cc = (int)(pk >> 20);
    float4 r0 = {0.f, 0.f, 0.f, 0.f}, r1 = r0, r2 = r0;
    if (cc) {
      int sc = (int)(pk & 0xFFFFFu);
      int x = p >> 14, y = (p >> 7) & 127, z = p & 127;
      const int off[6] = {-(1 << 14), (1 << 14), -(1 << 7), (1 << 7), -1, 1};
      const bool inb[6] = {x > 0, x < 127, y > 0, y < 127, z > 0, z < 127};
      float f[6], m[6];
#pragma unroll
      for (int k = 0; k < 6; k++) {
        int sn = 0, cn = 0;
        if (inb[k]) {
          unsigned pn = P[p + off[k]];
          cn = (int)(pn >> 20);
          sn = (int)(pn & 0xFFFFFu);
        }
        if (cn) {
          long long d = (long long)sn * cc - (long long)sc * cn;
          if (d < 0) d = -d;
          f[k] = (100ll * d < (long long)cn * cc) ? 1.f : 0.f;
          m[k] = 1.f;
        } else {
          f[k] = 0.f;                          // vc >= 1 so |0-vc| >= 1
          m[k] = 0.f;
        }
      }
      r0 = {f[0], f[1], f[2], f[3]};
      r1 = {f[4], f[5], m[0], m[1]};
      r2 = {m[2], m[3], m[4], m[5]};
    }
    float4* o = (float4*)(out + 12ll * p);
    o[0] = r0; o[1] = r1; o[2] = r2;
    return;
  }
  int t = p - GS3;
  const double *vs, *as;
  int ls, q;
  long long obase;
  if (t < NS1) { q = t; vs = vs1; as = as1; ls = 6; obase = OB1; }
  else if (t < NS1 + NS2) { q = t - NS1; vs = vs2; as = as2; ls = 5; obase = OB2; }
  else if (t < NS1 + NS2 + NS3) { q = t - NS1 - NS2; vs = vs3; as = as3; ls = 4; obase = OB3; }
  else if (t < NS1 + NS2 + NS3 + NS4) { q = t - NS1 - NS2 - NS3; vs = vs4; as = as4; ls = 3; obase = OB4; }
  else if (t < NSALL) { q = t - NS1 - NS2 - NS3 - NS4; vs = vs5; as = as5; ls = 2; obase = OB5; }
  else return;

  int Ss = 1 << ls;
  int X = q >> (2 * ls), Y = (q >> ls) & (Ss - 1), Z = q & (Ss - 1);
  double ac = as[q];
  float4 r0 = {0.f, 0.f, 0.f, 0.f}, r1 = r0, r2 = r0;
  if (ac > 0.0) {
    double vc = vs[q] / ac;
    const int off[6] = {-(Ss * Ss), Ss * Ss, -Ss, Ss, -1, 1};
    const bool inb[6] = {X > 0, X < Ss - 1, Y > 0, Y < Ss - 1, Z > 0, Z < Ss - 1};
    float f[6], m[6];
#pragma unroll
    for (int k = 0; k < 6; k++) {
      double van = 0.0;
      if (inb[k]) {
        double an = as[q + off[k]];
        if (an > 0.0) van = vs[q + off[k]] / an;
      }
      f[k] = (fabs(van - vc) < 0.01) ? 1.f : 0.f;
      m[k] = (van > 0.0) ? 1.f : 0.f;
    }
    r0 = {f[0], f[1], f[2], f[3]};
    r1 = {f[4], f[5], m[0], m[1]};
    r2 = {m[2], m[3], m[4], m[5]};
  }
  float4* o = (float4*)(out + obase + 12ll * q);
  o[0] = r0; o[1] = r1; o[2] = r2;
}

// ---------------------------------------------------------------------------
extern "C" void kernel_launch(void* const* d_in, const int* in_sizes, int n_in,
                              void* d_out, int out_size, void* d_ws, size_t ws_size,
                              hipStream_t stream) {
  const int* coords = (const int*)d_in[0];
  const float* inst = (const float*)d_in[1];
  int N = in_sizes[1];            // 4,000,000 points
  float* out = (float*)d_out;

  // workspace layout
  char* base = (char*)d_ws;
  unsigned int* P = (unsigned int*)base;                 // 8 MB
  double* vs1 = (double*)(base + 8388608);
  double* as1 = vs1 + NS1;
  double* vs2 = as1 + NS1; double* as2 = vs2 + NS2;
  double* vs3 = as2 + NS2; double* as3 = vs3 + NS3;
  double* vs4 = as3 + NS3; double* as4 = vs4 + NS4;
  double* vs5 = as4 + NS4; double* as5 = vs5 + NS5;     // ends ~13.18 MB
  size_t cnt_off = 13182976;                             // 1KB-aligned
  unsigned int* cnt  = (unsigned int*)(base + cnt_off);
  unsigned int* bins = (unsigned int*)(base + cnt_off + 2048);
  size_t need = cnt_off + 2048 + (size_t)NREG * CAP * 4; // ~34.2 MB

  if (ws_size >= need) {
    zero_cnt_kernel<<<1, 256, 0, stream>>>(cnt);
    bin_kernel<<<(N + PPB - 1) / PPB, 256, 0, stream>>>(coords, inst, cnt, bins, N);
    build_kernel<<<NREG, 256, 0, stream>>>(cnt, bins, P);
  } else {
    hipMemsetAsync(P, 0, (size_t)GS3 * 4, stream);
    scatter_kernel<<<(N + 255) / 256, 256, 0, stream>>>(coords, inst, P, N);
  }
  pool1_kernel<<<NS1 / 256, 256, 0, stream>>>(P, vs1, as1);
  poolRest_kernel<<<(NS2 + NS3 + NS4 * 64 + NS5 * 64) / 256, 256, 0, stream>>>(
      vs1, as1, vs2, as2, vs3, as3, vs4, as4, vs5, as5);
  out_kernel<<<(GS3 + NSALL + 255) / 256, 256, 0, stream>>>(
      P, vs1, as1, vs2, as2, vs3, as3, vs4, as4, vs5, as5, out);
}

// Round 7
// 103.578 us; speedup vs baseline: 2.1110x; 1.0889x over previous
//
#include <hip/hip_runtime.h>

#define GS3 2097152          // 128^3
#define NS1 262144           // 64^3
#define NS2 32768            // 32^3
#define NS3 4096             // 16^3
#define NS4 512              // 8^3
#define NS5 64               // 4^3
#define NSALL 299584         // NS1+NS2+NS3+NS4+NS5

// Output element offsets (float index) for each scale's block of [Ss^3, 12]
#define OB1 25165824
#define OB2 28311552
#define OB3 28704768
#define OB4 28753920
#define OB5 28760064

#define NREG 512             // regions: x (7b) * y-quadrant (2b)
#define RVOX 4096            // voxels per region: 32 (y) * 128 (z)
#define CAP  10240           // bin capacity per region (mean 7813, +27 sigma)
#define PPB  8192            // points per binning block

// ---------------------------------------------------------------------------
// 0) Zero the 512-word region-counter array.
// ---------------------------------------------------------------------------
__global__ __launch_bounds__(256) void zero_cnt_kernel(unsigned int* __restrict__ cnt) {
  cnt[threadIdx.x] = 0u;
  cnt[threadIdx.x + 256] = 0u;
}

// ---------------------------------------------------------------------------
// 1a) Binning with block-local counting sort: records are grouped by region
//     in LDS before writing, so global stores are coalesced runs per region
//     (previous version: 4M scattered 4B stores -> 32-64B granule each).
//     Record: (region<<18) | (localvoxel<<6) | label,  localvoxel=(y&31)<<7|z
// ---------------------------------------------------------------------------
__global__ __launch_bounds__(256) void bin_kernel(
    const int* __restrict__ coords, const float* __restrict__ inst,
    unsigned int* __restrict__ cnt, unsigned int* __restrict__ bins, int N) {
  __shared__ unsigned int lrec[PPB];     // 32 KB raw records
  __shared__ unsigned int srec[PPB];     // 32 KB region-sorted records
  __shared__ unsigned int hist[NREG];    // 2 KB: counts, then scatter cursor
  __shared__ unsigned int lofs[NREG];    // 2 KB: block-local region starts
  __shared__ unsigned int basec[NREG];   // 2 KB: global chunk base per region
  __shared__ unsigned int part[256];     // 1 KB: scan workspace
  __shared__ unsigned int total_sh;
  int tid = threadIdx.x;
  int start = blockIdx.x * PPB;
  for (int j = tid; j < NREG; j += 256) hist[j] = 0;
  __syncthreads();
  // phase 1: read points, build records in LDS, count per region
#pragma unroll
  for (int j = 0; j < PPB / 256; j++) {
    int i = start + j * 256 + tid;
    unsigned v = 0xFFFFFFFFu;
    if (i < N) {
      int x = coords[3 * i + 0];
      int y = coords[3 * i + 1];
      int z = coords[3 * i + 2];
      unsigned lab = (unsigned)inst[i] + 1u;                 // 1..50
      unsigned r = ((unsigned)x << 2) | ((unsigned)y >> 5);  // 9 bits
      v = (r << 18) | ((((unsigned)(y & 31) << 7) | (unsigned)z) << 6) | lab;
      atomicAdd(&hist[r], 1u);
    }
    lrec[j * 256 + tid] = v;
  }
  __syncthreads();
  // phase 2a: exclusive scan of hist[512] -> lofs (2 entries/thread)
  unsigned ha = hist[2 * tid], hb = hist[2 * tid + 1];
  part[tid] = ha + hb;
  __syncthreads();
  for (int o = 1; o < 256; o <<= 1) {
    unsigned v = part[tid];
    unsigned add = (tid >= o) ? part[tid - o] : 0u;
    __syncthreads();
    part[tid] = v + add;
    __syncthreads();
  }
  unsigned inc = part[tid];
  unsigned ex = inc - (ha + hb);
  lofs[2 * tid] = ex;
  lofs[2 * tid + 1] = ex + ha;
  if (tid == 255) total_sh = inc;        // total valid records in block
  __syncthreads();
  // phase 2b: reserve per-region chunks in global bins
  for (int j = tid; j < NREG; j += 256) {
    unsigned h = hist[j];
    basec[j] = h ? atomicAdd(&cnt[j], h) : 0u;
  }
  __syncthreads();
  for (int j = tid; j < NREG; j += 256) hist[j] = 0;   // reuse as cursor
  __syncthreads();
  // phase 3a: scatter records into region-sorted LDS buffer
#pragma unroll
  for (int j = 0; j < PPB / 256; j++) {
    unsigned v = lrec[j * 256 + tid];
    if (v != 0xFFFFFFFFu) {
      unsigned r = v >> 18;
      unsigned pos = lofs[r] + atomicAdd(&hist[r], 1u);
      srec[pos] = v;
    }
  }
  __syncthreads();
  // phase 3b: coalesced write-out (consecutive j -> consecutive addresses)
  unsigned total = total_sh;
  for (unsigned j = tid; j < total; j += 256) {
    unsigned v = srec[j];
    unsigned r = v >> 18;
    unsigned p = basec[r] + (j - lofs[r]);
    if (p < CAP) bins[r * CAP + p] = v & 0x3FFFFu;
  }
}

// ---------------------------------------------------------------------------
// 1b) Build P: one block per region, aggregate records in a 16KB LDS grid
//     (packed cnt<<20|sum, integer adds -> order-independent), coalesced store.
// ---------------------------------------------------------------------------
__global__ __launch_bounds__(256) void build_kernel(
    const unsigned int* __restrict__ cnt, const unsigned int* __restrict__ bins,
    unsigned int* __restrict__ P) {
  __shared__ unsigned int grid[RVOX];    // 16 KB
  int r = blockIdx.x;
  int tid = threadIdx.x;
  for (int j = tid; j < RVOX; j += 256) grid[j] = 0;
  __syncthreads();
  int n = min((int)cnt[r], CAP);
  for (int k = tid; k < n; k += 256) {
    unsigned v = bins[r * CAP + k];
    atomicAdd(&grid[v >> 6], (1u << 20) | (v & 63u));
  }
  __syncthreads();
  unsigned baseoff = ((unsigned)(r >> 2) << 14) | ((unsigned)(r & 3) << 12);
  for (int j = tid; j < RVOX; j += 256) P[baseoff + j] = grid[j];
}

// ---------------------------------------------------------------------------
// 1-fallback) direct atomic scatter (used only if ws_size too small for bins)
// ---------------------------------------------------------------------------
__global__ __launch_bounds__(256) void scatter_kernel(
    const int* __restrict__ coords, const float* __restrict__ inst,
    unsigned int* __restrict__ P, int N) {
  int i = blockIdx.x * blockDim.x + threadIdx.x;
  if (i >= N) return;
  int x = coords[3 * i + 0];
  int y = coords[3 * i + 1];
  int z = coords[3 * i + 2];
  unsigned lab = (unsigned)inst[i] + 1u;
  atomicAdd(&P[(x << 14) + (y << 7) + z], (1u << 20) | lab);
}

// ---------------------------------------------------------------------------
// 2) Pool 128^3 -> 64^3 in double
// ---------------------------------------------------------------------------
__global__ __launch_bounds__(256) void pool1_kernel(
    const unsigned int* __restrict__ P,
    double* __restrict__ vs1, double* __restrict__ as1) {
  int q = blockIdx.x * blockDim.x + threadIdx.x;
  if (q >= NS1) return;
  int X = q >> 12, Y = (q >> 6) & 63, Z = q & 63;
  double vs = 0.0, as = 0.0;
#pragma unroll
  for (int dx = 0; dx < 2; dx++)
#pragma unroll
    for (int dy = 0; dy < 2; dy++)
#pragma unroll
      for (int dz = 0; dz < 2; dz++) {
        int p = (((2 * X + dx) << 14) + ((2 * Y + dy) << 7) + (2 * Z + dz));
        unsigned pk = P[p];
        unsigned c = pk >> 20;
        if (c) {
          vs += (double)(pk & 0xFFFFFu) / (double)c;
          as += 1.0;
        }
      }
  vs1[q] = vs;
  as1[q] = as;
}

// ---------------------------------------------------------------------------
// 3) Pool scales 2..5 from scale-1 sums (sums are additive).
// ---------------------------------------------------------------------------
__global__ __launch_bounds__(256) void poolRest_kernel(
    const double* __restrict__ vs1, const double* __restrict__ as1,
    double* __restrict__ vs2, double* __restrict__ as2,
    double* __restrict__ vs3, double* __restrict__ as3,
    double* __restrict__ vs4, double* __restrict__ as4,
    double* __restrict__ vs5, double* __restrict__ as5) {
  int t = blockIdx.x * blockDim.x + threadIdx.x;

  if (t < NS2) {
    int q = t;
    int X = q >> 10, Y = (q >> 5) & 31, Z = q & 31;
    double vs = 0.0, as = 0.0;
#pragma unroll
    for (int dx = 0; dx < 2; dx++)
#pragma unroll
      for (int dy = 0; dy < 2; dy++)
#pragma unroll
        for (int dz = 0; dz < 2; dz++) {
          int p = ((((X << 1) + dx) << 12) + (((Y << 1) + dy) << 6) + ((Z << 1) + dz));
          vs += vs1[p];
          as += as1[p];
        }
    vs2[q] = vs;
    as2[q] = as;
    return;
  }
  t -= NS2;
  if (t < NS3) {
    int q = t;
    int X = q >> 8, Y = (q >> 4) & 15, Z = q & 15;
    double vs = 0.0, as = 0.0;
    for (int dx = 0; dx < 4; dx++)
      for (int dy = 0; dy < 4; dy++)
#pragma unroll
        for (int dz = 0; dz < 4; dz++) {
          int p = ((((X << 2) + dx) << 12) + (((Y << 2) + dy) << 6) + ((Z << 2) + dz));
          vs += vs1[p];
          as += as1[p];
        }
    vs3[q] = vs;
    as3[q] = as;
    return;
  }
  t -= NS3;
  if (t < NS4 * 64) {
    int w = t >> 6, lane = t & 63;
    int X = w >> 6, Y = (w >> 3) & 7, Z = w & 7;
    double vs = 0.0, as = 0.0;
#pragma unroll
    for (int j = 0; j < 8; j++) {
      int c = lane * 8 + j;
      int dx = c >> 6, dy = (c >> 3) & 7, dz = c & 7;
      int p = ((((X << 3) + dx) << 12) + (((Y << 3) + dy) << 6) + ((Z << 3) + dz));
      vs += vs1[p];
      as += as1[p];
    }
    for (int o = 32; o > 0; o >>= 1) {
      vs += __shfl_down(vs, o, 64);
      as += __shfl_down(as, o, 64);
    }
    if (lane == 0) { vs4[w] = vs; as4[w] = as; }
    return;
  }
  t -= NS4 * 64;
  if (t < NS5 * 64) {
    int w = t >> 6, lane = t & 63;
    int X = w >> 4, Y = (w >> 2) & 3, Z = w & 3;
    double vs = 0.0, as = 0.0;
    for (int j = 0; j < 64; j++) {
      int c = lane * 64 + j;
      int dx = c >> 8, dy = (c >> 4) & 15, dz = c & 15;
      int p = ((((X << 4) + dx) << 12) + (((Y << 4) + dy) << 6) + ((Z << 4) + dz));
      vs += vs1[p];
      as += as1[p];
    }
    for (int o = 32; o > 0; o >>= 1) {
      vs += __shfl_down(vs, o, 64);
      as += __shfl_down(as, o, 64);
    }
    if (lane == 0) { vs5[w] = vs; as5[w] = as; }
  }
}

// ---------------------------------------------------------------------------
// 4) Fused output kernel.
//    Threads [0, GS3): scale-0 via exact integer comparison
//      |sn/cn - sc/cc| < 0.01  <=>  100*|sn*cc - sc*cn| < cn*cc
//    Threads [GS3, GS3+NSALL): scales 1..5 via f64.
// ---------------------------------------------------------------------------
__global__ __launch_bounds__(256) void out_kernel(
    const unsigned int* __restrict__ P,
    const double* __restrict__ vs1, const double* __restrict__ as1,
    const double* __restrict__ vs2, const double* __restrict__ as2,
    const double* __restrict__ vs3, const double* __restrict__ as3,
    const double* __restrict__ vs4, const double* __restrict__ as4,
    const double* __restrict__ vs5, const double* __restrict__ as5,
    float* __restrict__ out) {
  int p = blockIdx.x * blockDim.x + threadIdx.x;
  if (p < GS3) {
    unsigned pk = P[p];
    int cc = (int)(pk >> 20);
    float4 r0 = {0.f, 0.f, 0.f, 0.f}, r1 = r0, r2 = r0;
    if (cc) {
      int sc = (int)(pk & 0xFFFFFu);
      int x = p >> 14, y = (p >> 7) & 127, z = p & 127;
      const int off[6] = {-(1 << 14), (1 << 14), -(1 << 7), (1 << 7), -1, 1};
      const bool inb[6] = {x > 0, x < 127, y > 0, y < 127, z > 0, z < 127};
      float f[6], m[6];
#pragma unroll
      for (int k = 0; k < 6; k++) {
        int sn = 0, cn = 0;
        if (inb[k]) {
          unsigned pn = P[p + off[k]];
          cn = (int)(pn >> 20);
          sn = (int)(pn & 0xFFFFFu);
        }
        if (cn) {
          long long d = (long long)sn * cc - (long long)sc * cn;
          if (d < 0) d = -d;
          f[k] = (100ll * d < (long long)cn * cc) ? 1.f : 0.f;
          m[k] = 1.f;
        } else {
          f[k] = 0.f;                          // vc >= 1 so |0-vc| >= 1
          m[k] = 0.f;
        }
      }
      r0 = {f[0], f[1], f[2], f[3]};
      r1 = {f[4], f[5], m[0], m[1]};
      r2 = {m[2], m[3], m[4], m[5]};
    }
    float4* o = (float4*)(out + 12ll * p);
    o[0] = r0; o[1] = r1; o[2] = r2;
    return;
  }
  int t = p - GS3;
  const double *vs, *as;
  int ls, q;
  long long obase;
  if (t < NS1) { q = t; vs = vs1; as = as1; ls = 6; obase = OB1; }
  else if (t < NS1 + NS2) { q = t - NS1; vs = vs2; as = as2; ls = 5; obase = OB2; }
  else if (t < NS1 + NS2 + NS3) { q = t - NS1 - NS2; vs = vs3; as = as3; ls = 4; obase = OB3; }
  else if (t < NS1 + NS2 + NS3 + NS4) { q = t - NS1 - NS2 - NS3; vs = vs4; as = as4; ls = 3; obase = OB4; }
  else if (t < NSALL) { q = t - NS1 - NS2 - NS3 - NS4; vs = vs5; as = as5; ls = 2; obase = OB5; }
  else return;

  int Ss = 1 << ls;
  int X = q >> (2 * ls), Y = (q >> ls) & (Ss - 1), Z = q & (Ss - 1);
  double ac = as[q];
  float4 r0 = {0.f, 0.f, 0.f, 0.f}, r1 = r0, r2 = r0;
  if (ac > 0.0) {
    double vc = vs[q] / ac;
    const int off[6] = {-(Ss * Ss), Ss * Ss, -Ss, Ss, -1, 1};
    const bool inb[6] = {X > 0, X < Ss - 1, Y > 0, Y < Ss - 1, Z > 0, Z < Ss - 1};
    float f[6], m[6];
#pragma unroll
    for (int k = 0; k < 6; k++) {
      double van = 0.0;
      if (inb[k]) {
        double an = as[q + off[k]];
        if (an > 0.0) van = vs[q + off[k]] / an;
      }
      f[k] = (fabs(van - vc) < 0.01) ? 1.f : 0.f;
      m[k] = (van > 0.0) ? 1.f : 0.f;
    }
    r0 = {f[0], f[1], f[2], f[3]};
    r1 = {f[4], f[5], m[0], m[1]};
    r2 = {m[2], m[3], m[4], m[5]};
  }
  float4* o = (float4*)(out + obase + 12ll * q);
  o[0] = r0; o[1] = r1; o[2] = r2;
}

// ---------------------------------------------------------------------------
extern "C" void kernel_launch(void* const* d_in, const int* in_sizes, int n_in,
                              void* d_out, int out_size, void* d_ws, size_t ws_size,
                              hipStream_t stream) {
  const int* coords = (const int*)d_in[0];
  const float* inst = (const float*)d_in[1];
  int N = in_sizes[1];            // 4,000,000 points
  float* out = (float*)d_out;

  // workspace layout
  char* base = (char*)d_ws;
  unsigned int* P = (unsigned int*)base;                 // 8 MB
  double* vs1 = (double*)(base + 8388608);
  double* as1 = vs1 + NS1;
  double* vs2 = as1 + NS1; double* as2 = vs2 + NS2;
  double* vs3 = as2 + NS2; double* as3 = vs3 + NS3;
  double* vs4 = as3 + NS3; double* as4 = vs4 + NS4;
  double* vs5 = as4 + NS4; double* as5 = vs5 + NS5;     // ends ~13.18 MB
  size_t cnt_off = 13182976;                             // 1KB-aligned
  unsigned int* cnt  = (unsigned int*)(base + cnt_off);
  unsigned int* bins = (unsigned int*)(base + cnt_off + 2048);
  size_t need = cnt_off + 2048 + (size_t)NREG * CAP * 4; // ~34.2 MB

  if (ws_size >= need) {
    zero_cnt_kernel<<<1, 256, 0, stream>>>(cnt);
    bin_kernel<<<(N + PPB - 1) / PPB, 256, 0, stream>>>(coords, inst, cnt, bins, N);
    build_kernel<<<NREG, 256, 0, stream>>>(cnt, bins, P);
  } else {
    hipMemsetAsync(P, 0, (size_t)GS3 * 4, stream);
    scatter_kernel<<<(N + 255) / 256, 256, 0, stream>>>(coords, inst, P, N);
  }
  pool1_kernel<<<NS1 / 256, 256, 0, stream>>>(P, vs1, as1);
  poolRest_kernel<<<(NS2 + NS3 + NS4 * 64 + NS5 * 64) / 256, 256, 0, stream>>>(
      vs1, as1, vs2, as2, vs3, as3, vs4, as4, vs5, as5);
  out_kernel<<<(GS3 + NSALL + 255) / 256, 256, 0, stream>>>(
      P, vs1, as1, vs2, as2, vs3, as3, vs4, as4, vs5, as5, out);
}